// Round 17
// baseline (820.761 us; speedup 1.0000x reference)
//
#include <hip/hip_runtime.h>
#include <stdint.h>
#include <stddef.h>

using short8 = __attribute__((ext_vector_type(8))) short;
using short4v = __attribute__((ext_vector_type(4))) short;
using f32x4  = __attribute__((ext_vector_type(4))) float;

#define BB 8
#define LL 2048
#define DD 768
#define KS 8
#define ND 2304           // 3*DD
#define NT 12             // DD/64 k-tiles
#define NBD 12            // DD/64 d-blocks

__device__ __forceinline__ float bf2f(unsigned short u) {
  union { uint32_t i; float f; } v; v.i = ((uint32_t)u) << 16; return v.f;
}
__device__ __forceinline__ unsigned short f2bf(float f) {
  union { float f; uint32_t i; } v; v.f = f;
  return (unsigned short)((v.i + 0x7FFFu + ((v.i >> 16) & 1u)) >> 16);
}
__device__ __forceinline__ float sigm(float x) { return 1.0f / (1.0f + __expf(-x)); }
__device__ __forceinline__ float tanh_fast(float x) {
  return 2.0f / (1.0f + __expf(-2.0f * x)) - 1.0f;
}
// global -> LDS DMA, 16B per lane. lds MUST be wave-uniform (HW adds lane*16).
__device__ __forceinline__ void gload_lds16(const void* g, void* lds) {
  __builtin_amdgcn_global_load_lds(
      (const __attribute__((address_space(1))) void*)g,
      (__attribute__((address_space(3))) void*)lds, 16, 0, 0);
}

// group-swizzle: groups of 8 m-blocks x nbn n-blocks; gm fastest within group.
__device__ __forceinline__ void swz_blocks(int bid, int nbm, int nbn,
                                           int* mb, int* nb) {
  int gsz = 8 * nbn;
  int g = bid / gsz;
  int rem = bid - g * gsz;
  int gg = nbm - g * 8; if (gg > 8) gg = 8;
  *nb = rem / gg;
  *mb = g * 8 + (rem - *nb * gg);
}

// ---- zero a small buffer ----------------------------------------------------
__global__ void zero_k(unsigned short* p, int n) {
  int i = blockIdx.x * 256 + threadIdx.x;
  if (i < n) p[i] = 0;
}

// ---- dtype detector: flag=1 if x is bf16 pairs, 0 if fp32 -----------------
__global__ void detect_k(const uint32_t* __restrict__ x, int* __restrict__ flag) {
  int t = threadIdx.x;  // 64 threads
  uint32_t w = x[t * 16];
  int e = (int)((w >> 7) & 0xFF);
  int isbf = (e >= 112 && e <= 136) ? 1 : 0;
  unsigned long long m = __ballot(isbf);
  if (t == 0) *flag = (__popcll(m) >= 32) ? 1 : 0;
}

// ---- transpose [R][C] -> [C][R], dual-dtype in, bf16 out ------------------
__global__ void transpose_k(const void* __restrict__ in,
                            unsigned short* __restrict__ out, int R, int C,
                            const int* __restrict__ flagp) {
  const bool bf = (*flagp != 0);
  __shared__ unsigned short t[32][33];
  int c0 = blockIdx.x * 32, r0 = blockIdx.y * 32;
  int tx = threadIdx.x, ty = threadIdx.y;  // block (32,8)
#pragma unroll
  for (int i = ty; i < 32; i += 8) {
    size_t idx = (size_t)(r0 + i) * C + c0 + tx;
    t[i][tx] = bf ? ((const unsigned short*)in)[idx]
                  : f2bf(((const float*)in)[idx]);
  }
  __syncthreads();
#pragma unroll
  for (int i = ty; i < 32; i += 8)
    out[(size_t)(c0 + i) * R + r0 + tx] = t[tx][i];
}

// ---- bias convert -> bf16 --------------------------------------------------
__global__ void conv_bias(const void* __restrict__ in,
                          unsigned short* __restrict__ out, int n,
                          const int* __restrict__ flagp) {
  const bool bf = (*flagp != 0);
  int i = blockIdx.x * 256 + threadIdx.x;
  if (i >= n) return;
  out[i] = bf ? ((const unsigned short*)in)[i] : f2bf(((const float*)in)[i]);
}

// ---- conv_x (fp32 mode ONLY): build padded bf16 chunk xpadc ---------------
__global__ void conv_x(const void* __restrict__ xv,
                       unsigned short* __restrict__ xpadc,
                       int Uc, int t0, int total8,
                       const int* __restrict__ flagp) {
  if (*flagp != 0) return;  // bf16 mode: gemm_gx reads x directly
  int idx = blockIdx.x * 256 + threadIdx.x;   // one short8 = 8 elems
  if (idx >= total8) return;
  size_t e = (size_t)idx * 8;
  int d = (int)(e % DD);
  size_t ru = e / DD;
  int u = (int)(ru % Uc);
  int b = (int)(ru / Uc);
  int p = t0 + u;
  short8 v = {0, 0, 0, 0, 0, 0, 0, 0};
  if (p >= KS - 1) {
    size_t base = ((size_t)b * LL + (p - (KS - 1))) * DD + d;
    const float* fp = (const float*)xv + base;
    float4 a = *(const float4*)fp, b4 = *(const float4*)(fp + 4);
    v[0] = (short)f2bf(a.x); v[1] = (short)f2bf(a.y);
    v[2] = (short)f2bf(a.z); v[3] = (short)f2bf(a.w);
    v[4] = (short)f2bf(b4.x); v[5] = (short)f2bf(b4.y);
    v[6] = (short)f2bf(b4.z); v[7] = (short)f2bf(b4.w);
  }
  *(short8*)&xpadc[e] = v;
}

// ---- fused gx GEMM + step0: 128m x 64d x 3 gates --------------------------
// T3-minimum pipeline: LDS dbuf, stage(t+1) issued BEFORE compute(t), ONE
// __syncthreads per k-tile. Writes packed gx + h0.
__global__ __launch_bounds__(256, 2) void gemm_gx(
    const unsigned short* __restrict__ xbf, const unsigned short* __restrict__ xpadc,
    const unsigned short* __restrict__ zrow, const unsigned short* __restrict__ WT,
    const unsigned short* __restrict__ bih, const unsigned short* __restrict__ bhh,
    unsigned short* __restrict__ gxp, unsigned short* __restrict__ h0,
    int Mrows, int Uc, int Tcc, int t0, const int* __restrict__ flagp, int nbm) {
  __shared__ __align__(16) unsigned short Al[2][128 * 64];  // 32 KB
  __shared__ __align__(16) unsigned short Bl[2][192 * 64];  // 48 KB
  const bool bfm = (*flagp != 0);
  const int tid = threadIdx.x, lane = tid & 63, wv = tid >> 6;
  const int wm = wv >> 1, wd = wv & 1;
  int mb, db; swz_blocks(blockIdx.x, nbm, NBD, &mb, &db);
  const int m0 = mb * 128, d0 = db * 64;
  const int h16 = lane >> 4, l16 = lane & 15;

  const int r0i = tid >> 3;
  const int slotg = (tid & 7) ^ (r0i & 7);
  const unsigned short* asrc[4];
#pragma unroll
  for (int it = 0; it < 4; ++it) {
    int grow = m0 + it * 32 + r0i; if (grow >= Mrows) grow = Mrows - 1;
    if (bfm) {
      int b = grow / Uc, u = grow - b * Uc;
      int p = t0 + u;
      asrc[it] = (p < KS - 1)
          ? (zrow + slotg * 8)
          : (xbf + ((size_t)b * LL + (p - (KS - 1))) * DD + slotg * 8);
    } else {
      asrc[it] = xpadc + (size_t)grow * DD + slotg * 8;
    }
  }
  const unsigned short* bbase = WT + (size_t)(d0 + r0i) * DD + slotg * 8;

#define GX_STAGE(KT, BUF)                                                     \
  {                                                                           \
    const int ko_ = (KT) * 64;                                                \
    char* ad_ = (char*)Al[BUF] + wv * 1024;                                   \
    char* bd_ = (char*)Bl[BUF] + wv * 1024;                                   \
    _Pragma("unroll")                                                         \
    for (int it = 0; it < 4; ++it)                                            \
      gload_lds16(asrc[it] + ko_, ad_ + it * 4096);                           \
    _Pragma("unroll")                                                         \
    for (int it = 0; it < 6; ++it) {                                          \
      const size_t boff_ = (size_t)(it >> 1) * (DD * DD) +                    \
                           (size_t)(it & 1) * (32 * DD);                      \
      gload_lds16(bbase + boff_ + ko_, bd_ + it * 4096);                      \
    }                                                                         \
  }

  f32x4 acc[4][2][3] = {};

  GX_STAGE(0, 0);
  __syncthreads();

  int cur = 0;
  for (int kt = 0; kt < NT; ++kt) {
    if (kt + 1 < NT) GX_STAGE(kt + 1, cur ^ 1);
    const unsigned short* Ab = Al[cur];
    const unsigned short* Bb = Bl[cur];
#pragma unroll
    for (int s = 0; s < 2; ++s) {
      short8 af[4];
#pragma unroll
      for (int i = 0; i < 4; ++i) {
        int row = wm * 64 + i * 16 + l16;
        af[i] = *(const short8*)&Ab[row * 64 + (((s * 4 + h16) ^ (row & 7)) * 8)];
      }
      short8 bfr[2][3];
#pragma unroll
      for (int jd = 0; jd < 2; ++jd)
#pragma unroll
        for (int g = 0; g < 3; ++g) {
          int row = g * 64 + wd * 32 + jd * 16 + l16;
          bfr[jd][g] = *(const short8*)&Bb[row * 64 + (((s * 4 + h16) ^ (row & 7)) * 8)];
        }
#pragma unroll
      for (int i = 0; i < 4; ++i)
#pragma unroll
        for (int jd = 0; jd < 2; ++jd)
#pragma unroll
          for (int g = 0; g < 3; ++g)
            acc[i][jd][g] = __builtin_amdgcn_mfma_f32_16x16x32_bf16(af[i], bfr[jd][g], acc[i][jd][g], 0, 0, 0);
    }
    __syncthreads();
    cur ^= 1;
  }
#undef GX_STAGE

  const int b0 = m0 / Uc;
  const int u00 = m0 - b0 * Uc;
#pragma unroll
  for (int jd = 0; jd < 2; ++jd) {
    int d = d0 + wd * 32 + jd * 16 + l16;
    float bir = bf2f(bih[d]), biz = bf2f(bih[DD + d]), bin_ = bf2f(bih[2 * DD + d]);
    float bhr = bf2f(bhh[d]), bhz = bf2f(bhh[DD + d]), bhn = bf2f(bhh[2 * DD + d]);
#pragma unroll
    for (int i = 0; i < 4; ++i) {
      int mbase = m0 + wm * 64 + i * 16 + 4 * h16;
#pragma unroll
      for (int r2 = 0; r2 < 4; ++r2) {
        int m = mbase + r2;
        if (m >= Mrows) continue;
        float gr = acc[i][jd][0][r2] + bir;
        float gz = acc[i][jd][1][r2] + biz;
        float gn = acc[i][jd][2][r2] + bin_;
        short4v pk;
        pk[0] = (short)f2bf(gr); pk[1] = (short)f2bf(gz);
        pk[2] = (short)f2bf(gn); pk[3] = 0;
        *(short4v*)(gxp + (size_t)m * (DD * 4) + d * 4) = pk;
        int uu = u00 + (m - m0);
        int b = b0;
        if (uu >= Uc) { b += 1; uu -= Uc; }
        if (uu < Tcc) {
          float r = sigm(gr + bhr);
          float z = sigm(gz + bhz);
          float n = tanh_fast(gn + r * bhn);
          h0[((size_t)b * Tcc + uu) * DD + d] = f2bf((1.0f - z) * n);
        }
      }
    }
  }
}

// ---- fused GEMM + GRU step j (j=1..7): T3-minimum pipeline ----------------
__global__ __launch_bounds__(256, 2) void gemm_gru_step(
    const unsigned short* __restrict__ Hc, const unsigned short* __restrict__ WT,
    const unsigned short* __restrict__ bhh, const unsigned short* __restrict__ gxp,
    int Uc, void* __restrict__ Hn, int hnBS, int hnOff, int j, int lgTc,
    const int* __restrict__ flagp, int isFinal, int nbm) {
  __shared__ __align__(16) unsigned short Al[2][128 * 64];  // 32 KB
  __shared__ __align__(16) unsigned short Bl[2][192 * 64];  // 48 KB
  const bool bfm = (*flagp != 0);
  const int tid = threadIdx.x, lane = tid & 63, wv = tid >> 6;
  const int wm = wv >> 1, wd = wv & 1;
  int mb, db; swz_blocks(blockIdx.x, nbm, NBD, &mb, &db);
  const int m0 = mb * 128, d0 = db * 64;
  const int h16 = lane >> 4, l16 = lane & 15;
  const int tmask = (1 << lgTc) - 1;

  const int r0i = tid >> 3;
  const int slotg = (tid & 7) ^ (r0i & 7);
  const unsigned short* abase = Hc + (size_t)(m0 + r0i) * DD + slotg * 8;
  const unsigned short* bbase = WT + (size_t)(d0 + r0i) * DD + slotg * 8;

#define GRU_STAGE(KT, BUF)                                                    \
  {                                                                           \
    const int ko_ = (KT) * 64;                                                \
    char* ad_ = (char*)Al[BUF] + wv * 1024;                                   \
    char* bd_ = (char*)Bl[BUF] + wv * 1024;                                   \
    _Pragma("unroll")                                                         \
    for (int it = 0; it < 4; ++it)                                            \
      gload_lds16(abase + (size_t)it * (32 * DD) + ko_, ad_ + it * 4096);     \
    _Pragma("unroll")                                                         \
    for (int it = 0; it < 6; ++it) {                                          \
      const size_t boff_ = (size_t)(it >> 1) * (DD * DD) +                    \
                           (size_t)(it & 1) * (32 * DD);                      \
      gload_lds16(bbase + boff_ + ko_, bd_ + it * 4096);                      \
    }                                                                         \
  }

  f32x4 acc[4][2][3] = {};

  GRU_STAGE(0, 0);
  __syncthreads();

  int cur = 0;
  for (int kt = 0; kt < NT; ++kt) {
    if (kt + 1 < NT) GRU_STAGE(kt + 1, cur ^ 1);
    const unsigned short* Ab = Al[cur];
    const unsigned short* Bb = Bl[cur];
#pragma unroll
    for (int s = 0; s < 2; ++s) {
      short8 af[4];
#pragma unroll
      for (int i = 0; i < 4; ++i) {
        int row = wm * 64 + i * 16 + l16;
        af[i] = *(const short8*)&Ab[row * 64 + (((s * 4 + h16) ^ (row & 7)) * 8)];
      }
      short8 bfr[2][3];
#pragma unroll
      for (int jd = 0; jd < 2; ++jd)
#pragma unroll
        for (int g = 0; g < 3; ++g) {
          int row = g * 64 + wd * 32 + jd * 16 + l16;
          bfr[jd][g] = *(const short8*)&Bb[row * 64 + (((s * 4 + h16) ^ (row & 7)) * 8)];
        }
#pragma unroll
      for (int i = 0; i < 4; ++i)
#pragma unroll
        for (int jd = 0; jd < 2; ++jd)
#pragma unroll
          for (int g = 0; g < 3; ++g)
            acc[i][jd][g] = __builtin_amdgcn_mfma_f32_16x16x32_bf16(af[i], bfr[jd][g], acc[i][jd][g], 0, 0, 0);
    }
    __syncthreads();
    cur ^= 1;
  }
#undef GRU_STAGE

#pragma unroll
  for (int jd = 0; jd < 2; ++jd) {
    int d = d0 + wd * 32 + jd * 16 + l16;
    float br = bf2f(bhh[d]), bz = bf2f(bhh[DD + d]), bn = bf2f(bhh[2 * DD + d]);
#pragma unroll
    for (int i = 0; i < 4; ++i) {
      int mbase = m0 + wm * 64 + i * 16 + 4 * h16;
#pragma unroll
      for (int r2 = 0; r2 < 4; ++r2) {
        int m = mbase + r2;
        int b = m >> lgTc, t = m & tmask;
        size_t gxrow = (size_t)b * Uc + t + j;
        short4v pk = *(const short4v*)(gxp + gxrow * (DD * 4) + d * 4);
        float xr = bf2f((unsigned short)pk[0]);
        float xz = bf2f((unsigned short)pk[1]);
        float xn = bf2f((unsigned short)pk[2]);
        float gr = acc[i][jd][0][r2] + br;
        float gz = acc[i][jd][1][r2] + bz;
        float gn = acc[i][jd][2][r2] + bn;
        float rr = sigm(xr + gr);
        float zz = sigm(xz + gz);
        float nn = tanh_fast(xn + rr * gn);
        float ho = bf2f(Hc[(size_t)m * DD + d]);
        float val = (1.0f - zz) * nn + zz * ho;
        size_t hnrow = (size_t)b * hnBS + hnOff + t;
        if (isFinal && !bfm) ((float*)Hn)[hnrow * DD + d] = val;
        else ((unsigned short*)Hn)[hnrow * DD + d] = f2bf(val);
      }
    }
  }
}

extern "C" void kernel_launch(void* const* d_in, const int* in_sizes, int n_in,
                              void* d_out, int out_size, void* d_ws, size_t ws_size,
                              hipStream_t stream) {
  const void* x    = d_in[0];
  const void* w_ih = d_in[1];
  const void* w_hh = d_in[2];
  const void* b_ih = d_in[3];
  const void* b_hh = d_in[4];

  const size_t wTbytes = (size_t)ND * DD * 2;  // 3,538,944 B
  const size_t hdr = 2 * wTbytes + 2 * 4608 + 4096 + 4096;  // + zrow page

  // --- pick chunk size Tc (gx packed: 8 B per (m,d)) ---
  int Tc = 64;
  for (int tc = 2048; tc >= 64; tc >>= 1) {
    size_t hBsz  = (size_t)BB * tc * DD * 2;
    size_t xpsz  = (size_t)BB * (tc + KS - 1) * DD * 2;
    size_t uni   = hBsz > xpsz ? hBsz : xpsz;
    size_t need = hdr +
                  (size_t)BB * (tc + KS - 1) * DD * 8 +     // packed gx chunk
                  (size_t)BB * tc * DD * 2 +                // hA
                  uni;                                      // hB / xpadc union
    if (need <= ws_size) { Tc = tc; break; }
  }
  int lgTc = 0; while ((1 << lgTc) < Tc) ++lgTc;
  const int Uc = Tc + KS - 1;
  const int Mc = BB * Tc;
  const int Mg = BB * Uc;

  char* ws = (char*)d_ws;
  unsigned short* wihT = (unsigned short*)ws; ws += wTbytes;
  unsigned short* whhT = (unsigned short*)ws; ws += wTbytes;
  unsigned short* bihB = (unsigned short*)ws; ws += 4608;
  unsigned short* bhhB = (unsigned short*)ws; ws += 4608;
  int* flag            = (int*)ws;            ws += 4096;
  unsigned short* zrow = (unsigned short*)ws; ws += 4096;
  unsigned short* gxc  = (unsigned short*)ws; ws += (size_t)Mg * DD * 8;
  unsigned short* hA   = (unsigned short*)ws; ws += (size_t)Mc * DD * 2;
  unsigned short* hB   = (unsigned short*)ws;       // union with xpadc
  unsigned short* xpadc = hB;

  detect_k<<<1, 64, 0, stream>>>((const uint32_t*)x, flag);
  zero_k<<<8, 256, 0, stream>>>(zrow, 2048);
  transpose_k<<<dim3(ND / 32, DD / 32), dim3(32, 8), 0, stream>>>(w_ih, wihT, DD, ND, flag);
  transpose_k<<<dim3(ND / 32, DD / 32), dim3(32, 8), 0, stream>>>(w_hh, whhT, DD, ND, flag);
  conv_bias<<<(ND + 255) / 256, 256, 0, stream>>>(b_ih, bihB, ND, flag);
  conv_bias<<<(ND + 255) / 256, 256, 0, stream>>>(b_hh, bhhB, ND, flag);

  const int nbmGx = (Mg + 127) / 128;
  const int nbmGru = Mc / 128;

  for (int t0 = 0; t0 < LL; t0 += Tc) {
    // fp32 mode only: materialize padded bf16 x chunk (aliases hB)
    int total8 = Mg * (DD / 8);
    conv_x<<<(total8 + 255) / 256, 256, 0, stream>>>(x, xpadc, Uc, t0, total8, flag);

    // fused: packed gx + GRU step 0 (h0 -> hA)
    gemm_gx<<<nbmGx * NBD, 256, 0, stream>>>(
        (const unsigned short*)x, xpadc, zrow, wihT, bihB, bhhB, gxc, hA,
        Mg, Uc, Tc, t0, flag, nbmGx);

    unsigned short* cur = hA;
    for (int j = 1; j <= 7; ++j) {
      int isFinal = (j == 7);
      void* dst = isFinal ? d_out : (void*)((cur == hA) ? hB : hA);
      int hnBS = isFinal ? LL : Tc;
      int hnOff = isFinal ? t0 : 0;
      gemm_gru_step<<<nbmGru * NBD, 256, 0, stream>>>(
          cur, whhT, bhhB, gxc, Uc, dst, hnBS, hnOff, j, lgTc, flag, isFinal, nbmGru);
      if (!isFinal) cur = (cur == hA) ? hB : hA;
    }
  }
}

// Round 18
// 704.497 us; speedup vs baseline: 1.1650x; 1.1650x over previous
//
#include <hip/hip_runtime.h>
#include <stdint.h>
#include <stddef.h>

using short8 = __attribute__((ext_vector_type(8))) short;
using short4v = __attribute__((ext_vector_type(4))) short;
using f32x4  = __attribute__((ext_vector_type(4))) float;

#define BB 8
#define LL 2048
#define DD 768
#define KS 8
#define ND 2304           // 3*DD
#define NT 12             // DD/64 k-tiles
#define NBD 12            // DD/64 d-blocks

__device__ __forceinline__ float bf2f(unsigned short u) {
  union { uint32_t i; float f; } v; v.i = ((uint32_t)u) << 16; return v.f;
}
__device__ __forceinline__ unsigned short f2bf(float f) {
  union { float f; uint32_t i; } v; v.f = f;
  return (unsigned short)((v.i + 0x7FFFu + ((v.i >> 16) & 1u)) >> 16);
}
__device__ __forceinline__ float sigm(float x) { return 1.0f / (1.0f + __expf(-x)); }
__device__ __forceinline__ float tanh_fast(float x) {
  return 2.0f / (1.0f + __expf(-2.0f * x)) - 1.0f;
}
// global -> LDS DMA, 16B per lane. lds MUST be wave-uniform (HW adds lane*16).
__device__ __forceinline__ void gload_lds16(const void* g, void* lds) {
  __builtin_amdgcn_global_load_lds(
      (const __attribute__((address_space(1))) void*)g,
      (__attribute__((address_space(3))) void*)lds, 16, 0, 0);
}

// group-swizzle: groups of 8 m-blocks x nbn n-blocks; gm fastest within group.
__device__ __forceinline__ void swz_blocks(int bid, int nbm, int nbn,
                                           int* mb, int* nb) {
  int gsz = 8 * nbn;
  int g = bid / gsz;
  int rem = bid - g * gsz;
  int gg = nbm - g * 8; if (gg > 8) gg = 8;
  *nb = rem / gg;
  *mb = g * 8 + (rem - *nb * gg);
}

// ---- zero a small buffer ----------------------------------------------------
__global__ void zero_k(unsigned short* p, int n) {
  int i = blockIdx.x * 256 + threadIdx.x;
  if (i < n) p[i] = 0;
}

// ---- dtype detector: flag=1 if x is bf16 pairs, 0 if fp32 -----------------
__global__ void detect_k(const uint32_t* __restrict__ x, int* __restrict__ flag) {
  int t = threadIdx.x;  // 64 threads
  uint32_t w = x[t * 16];
  int e = (int)((w >> 7) & 0xFF);
  int isbf = (e >= 112 && e <= 136) ? 1 : 0;
  unsigned long long m = __ballot(isbf);
  if (t == 0) *flag = (__popcll(m) >= 32) ? 1 : 0;
}

// ---- transpose [R][C] -> [C][R], dual-dtype in, bf16 out ------------------
__global__ void transpose_k(const void* __restrict__ in,
                            unsigned short* __restrict__ out, int R, int C,
                            const int* __restrict__ flagp) {
  const bool bf = (*flagp != 0);
  __shared__ unsigned short t[32][33];
  int c0 = blockIdx.x * 32, r0 = blockIdx.y * 32;
  int tx = threadIdx.x, ty = threadIdx.y;  // block (32,8)
#pragma unroll
  for (int i = ty; i < 32; i += 8) {
    size_t idx = (size_t)(r0 + i) * C + c0 + tx;
    t[i][tx] = bf ? ((const unsigned short*)in)[idx]
                  : f2bf(((const float*)in)[idx]);
  }
  __syncthreads();
#pragma unroll
  for (int i = ty; i < 32; i += 8)
    out[(size_t)(c0 + i) * R + r0 + tx] = t[tx][i];
}

// ---- bias convert -> bf16 --------------------------------------------------
__global__ void conv_bias(const void* __restrict__ in,
                          unsigned short* __restrict__ out, int n,
                          const int* __restrict__ flagp) {
  const bool bf = (*flagp != 0);
  int i = blockIdx.x * 256 + threadIdx.x;
  if (i >= n) return;
  out[i] = bf ? ((const unsigned short*)in)[i] : f2bf(((const float*)in)[i]);
}

// ---- conv_x (fp32 mode ONLY): build padded bf16 chunk xpadc ---------------
__global__ void conv_x(const void* __restrict__ xv,
                       unsigned short* __restrict__ xpadc,
                       int Uc, int t0, int total8,
                       const int* __restrict__ flagp) {
  if (*flagp != 0) return;  // bf16 mode: gemm_gx reads x directly
  int idx = blockIdx.x * 256 + threadIdx.x;   // one short8 = 8 elems
  if (idx >= total8) return;
  size_t e = (size_t)idx * 8;
  int d = (int)(e % DD);
  size_t ru = e / DD;
  int u = (int)(ru % Uc);
  int b = (int)(ru / Uc);
  int p = t0 + u;
  short8 v = {0, 0, 0, 0, 0, 0, 0, 0};
  if (p >= KS - 1) {
    size_t base = ((size_t)b * LL + (p - (KS - 1))) * DD + d;
    const float* fp = (const float*)xv + base;
    float4 a = *(const float4*)fp, b4 = *(const float4*)(fp + 4);
    v[0] = (short)f2bf(a.x); v[1] = (short)f2bf(a.y);
    v[2] = (short)f2bf(a.z); v[3] = (short)f2bf(a.w);
    v[4] = (short)f2bf(b4.x); v[5] = (short)f2bf(b4.y);
    v[6] = (short)f2bf(b4.z); v[7] = (short)f2bf(b4.w);
  }
  *(short8*)&xpadc[e] = v;
}

// ---- fused gx GEMM + step0: 128m x 64d x 3 gates --------------------------
// Round-16 structure (single LDS buffer, 2 barriers/tile, 3 blocks/CU)
// + T5 setprio around MFMA. Writes packed gx + h0.
__global__ __launch_bounds__(256, 3) void gemm_gx(
    const unsigned short* __restrict__ xbf, const unsigned short* __restrict__ xpadc,
    const unsigned short* __restrict__ zrow, const unsigned short* __restrict__ WT,
    const unsigned short* __restrict__ bih, const unsigned short* __restrict__ bhh,
    unsigned short* __restrict__ gxp, unsigned short* __restrict__ h0,
    int Mrows, int Uc, int Tcc, int t0, const int* __restrict__ flagp, int nbm) {
  __shared__ __align__(16) unsigned short Al[128 * 64];  // 16 KB
  __shared__ __align__(16) unsigned short Bl[192 * 64];  // 24 KB
  const bool bfm = (*flagp != 0);
  const int tid = threadIdx.x, lane = tid & 63, wv = tid >> 6;
  const int wm = wv >> 1, wd = wv & 1;
  int mb, db; swz_blocks(blockIdx.x, nbm, NBD, &mb, &db);
  const int m0 = mb * 128, d0 = db * 64;
  const int h16 = lane >> 4, l16 = lane & 15;

  const int r0i = tid >> 3;
  const int slotg = (tid & 7) ^ (r0i & 7);
  const unsigned short* asrc[4];
#pragma unroll
  for (int it = 0; it < 4; ++it) {
    int grow = m0 + it * 32 + r0i; if (grow >= Mrows) grow = Mrows - 1;
    if (bfm) {
      int b = grow / Uc, u = grow - b * Uc;
      int p = t0 + u;
      asrc[it] = (p < KS - 1)
          ? (zrow + slotg * 8)
          : (xbf + ((size_t)b * LL + (p - (KS - 1))) * DD + slotg * 8);
    } else {
      asrc[it] = xpadc + (size_t)grow * DD + slotg * 8;
    }
  }
  const unsigned short* bbase = WT + (size_t)(d0 + r0i) * DD + slotg * 8;
  char* aldst = (char*)Al + (wv * 1024);
  char* bldst = (char*)Bl + (wv * 1024);

  f32x4 acc[4][2][3] = {};

  for (int kt = 0; kt < NT; ++kt) {
    const int ko = kt * 64;
#pragma unroll
    for (int it = 0; it < 4; ++it)
      gload_lds16(asrc[it] + ko, aldst + it * 4096);
#pragma unroll
    for (int it = 0; it < 6; ++it) {
      const size_t boff = (size_t)(it >> 1) * (DD * DD) + (size_t)(it & 1) * (32 * DD);
      gload_lds16(bbase + boff + ko, bldst + it * 4096);
    }
    __syncthreads();
#pragma unroll
    for (int s = 0; s < 2; ++s) {
      short8 af[4];
#pragma unroll
      for (int i = 0; i < 4; ++i) {
        int row = wm * 64 + i * 16 + l16;
        af[i] = *(const short8*)&Al[row * 64 + (((s * 4 + h16) ^ (row & 7)) * 8)];
      }
      short8 bfr[2][3];
#pragma unroll
      for (int jd = 0; jd < 2; ++jd)
#pragma unroll
        for (int g = 0; g < 3; ++g) {
          int row = g * 64 + wd * 32 + jd * 16 + l16;
          bfr[jd][g] = *(const short8*)&Bl[row * 64 + (((s * 4 + h16) ^ (row & 7)) * 8)];
        }
      __builtin_amdgcn_s_setprio(1);
#pragma unroll
      for (int i = 0; i < 4; ++i)
#pragma unroll
        for (int jd = 0; jd < 2; ++jd)
#pragma unroll
          for (int g = 0; g < 3; ++g)
            acc[i][jd][g] = __builtin_amdgcn_mfma_f32_16x16x32_bf16(af[i], bfr[jd][g], acc[i][jd][g], 0, 0, 0);
      __builtin_amdgcn_s_setprio(0);
    }
    if (kt + 1 < NT) __syncthreads();
  }

  const int b0 = m0 / Uc;
  const int u00 = m0 - b0 * Uc;
#pragma unroll
  for (int jd = 0; jd < 2; ++jd) {
    int d = d0 + wd * 32 + jd * 16 + l16;
    float bir = bf2f(bih[d]), biz = bf2f(bih[DD + d]), bin_ = bf2f(bih[2 * DD + d]);
    float bhr = bf2f(bhh[d]), bhz = bf2f(bhh[DD + d]), bhn = bf2f(bhh[2 * DD + d]);
#pragma unroll
    for (int i = 0; i < 4; ++i) {
      int mbase = m0 + wm * 64 + i * 16 + 4 * h16;
#pragma unroll
      for (int r2 = 0; r2 < 4; ++r2) {
        int m = mbase + r2;
        if (m >= Mrows) continue;
        float gr = acc[i][jd][0][r2] + bir;
        float gz = acc[i][jd][1][r2] + biz;
        float gn = acc[i][jd][2][r2] + bin_;
        short4v pk;
        pk[0] = (short)f2bf(gr); pk[1] = (short)f2bf(gz);
        pk[2] = (short)f2bf(gn); pk[3] = 0;
        *(short4v*)(gxp + (size_t)m * (DD * 4) + d * 4) = pk;
        int uu = u00 + (m - m0);
        int b = b0;
        if (uu >= Uc) { b += 1; uu -= Uc; }
        if (uu < Tcc) {
          float r = sigm(gr + bhr);
          float z = sigm(gz + bhz);
          float n = tanh_fast(gn + r * bhn);
          h0[((size_t)b * Tcc + uu) * DD + d] = f2bf((1.0f - z) * n);
        }
      }
    }
  }
}

// ---- fused GEMM + GRU step j (j=1..7): round-16 structure + setprio -------
__global__ __launch_bounds__(256, 3) void gemm_gru_step(
    const unsigned short* __restrict__ Hc, const unsigned short* __restrict__ WT,
    const unsigned short* __restrict__ bhh, const unsigned short* __restrict__ gxp,
    int Uc, void* __restrict__ Hn, int hnBS, int hnOff, int j, int lgTc,
    const int* __restrict__ flagp, int isFinal, int nbm) {
  __shared__ __align__(16) unsigned short Al[128 * 64];  // 16 KB
  __shared__ __align__(16) unsigned short Bl[192 * 64];  // 24 KB
  const bool bfm = (*flagp != 0);
  const int tid = threadIdx.x, lane = tid & 63, wv = tid >> 6;
  const int wm = wv >> 1, wd = wv & 1;
  int mb, db; swz_blocks(blockIdx.x, nbm, NBD, &mb, &db);
  const int m0 = mb * 128, d0 = db * 64;
  const int h16 = lane >> 4, l16 = lane & 15;
  const int tmask = (1 << lgTc) - 1;

  const int r0i = tid >> 3;
  const int slotg = (tid & 7) ^ (r0i & 7);
  const unsigned short* abase = Hc + (size_t)(m0 + r0i) * DD + slotg * 8;
  const unsigned short* bbase = WT + (size_t)(d0 + r0i) * DD + slotg * 8;
  char* aldst = (char*)Al + (wv * 1024);
  char* bldst = (char*)Bl + (wv * 1024);

  f32x4 acc[4][2][3] = {};

  for (int kt = 0; kt < NT; ++kt) {
    const int ko = kt * 64;
#pragma unroll
    for (int it = 0; it < 4; ++it)
      gload_lds16(abase + (size_t)it * (32 * DD) + ko, aldst + it * 4096);
#pragma unroll
    for (int it = 0; it < 6; ++it) {
      const size_t boff = (size_t)(it >> 1) * (DD * DD) + (size_t)(it & 1) * (32 * DD);
      gload_lds16(bbase + boff + ko, bldst + it * 4096);
    }
    __syncthreads();
#pragma unroll
    for (int s = 0; s < 2; ++s) {
      short8 af[4];
#pragma unroll
      for (int i = 0; i < 4; ++i) {
        int row = wm * 64 + i * 16 + l16;
        af[i] = *(const short8*)&Al[row * 64 + (((s * 4 + h16) ^ (row & 7)) * 8)];
      }
      short8 bfr[2][3];
#pragma unroll
      for (int jd = 0; jd < 2; ++jd)
#pragma unroll
        for (int g = 0; g < 3; ++g) {
          int row = g * 64 + wd * 32 + jd * 16 + l16;
          bfr[jd][g] = *(const short8*)&Bl[row * 64 + (((s * 4 + h16) ^ (row & 7)) * 8)];
        }
      __builtin_amdgcn_s_setprio(1);
#pragma unroll
      for (int i = 0; i < 4; ++i)
#pragma unroll
        for (int jd = 0; jd < 2; ++jd)
#pragma unroll
          for (int g = 0; g < 3; ++g)
            acc[i][jd][g] = __builtin_amdgcn_mfma_f32_16x16x32_bf16(af[i], bfr[jd][g], acc[i][jd][g], 0, 0, 0);
      __builtin_amdgcn_s_setprio(0);
    }
    if (kt + 1 < NT) __syncthreads();
  }

#pragma unroll
  for (int jd = 0; jd < 2; ++jd) {
    int d = d0 + wd * 32 + jd * 16 + l16;
    float br = bf2f(bhh[d]), bz = bf2f(bhh[DD + d]), bn = bf2f(bhh[2 * DD + d]);
#pragma unroll
    for (int i = 0; i < 4; ++i) {
      int mbase = m0 + wm * 64 + i * 16 + 4 * h16;
#pragma unroll
      for (int r2 = 0; r2 < 4; ++r2) {
        int m = mbase + r2;
        int b = m >> lgTc, t = m & tmask;
        size_t gxrow = (size_t)b * Uc + t + j;
        short4v pk = *(const short4v*)(gxp + gxrow * (DD * 4) + d * 4);
        float xr = bf2f((unsigned short)pk[0]);
        float xz = bf2f((unsigned short)pk[1]);
        float xn = bf2f((unsigned short)pk[2]);
        float gr = acc[i][jd][0][r2] + br;
        float gz = acc[i][jd][1][r2] + bz;
        float gn = acc[i][jd][2][r2] + bn;
        float rr = sigm(xr + gr);
        float zz = sigm(xz + gz);
        float nn = tanh_fast(xn + rr * gn);
        float ho = bf2f(Hc[(size_t)m * DD + d]);
        float val = (1.0f - zz) * nn + zz * ho;
        size_t hnrow = (size_t)b * hnBS + hnOff + t;
        if (isFinal && !bfm) ((float*)Hn)[hnrow * DD + d] = val;
        else ((unsigned short*)Hn)[hnrow * DD + d] = f2bf(val);
      }
    }
  }
}

extern "C" void kernel_launch(void* const* d_in, const int* in_sizes, int n_in,
                              void* d_out, int out_size, void* d_ws, size_t ws_size,
                              hipStream_t stream) {
  const void* x    = d_in[0];
  const void* w_ih = d_in[1];
  const void* w_hh = d_in[2];
  const void* b_ih = d_in[3];
  const void* b_hh = d_in[4];

  const size_t wTbytes = (size_t)ND * DD * 2;  // 3,538,944 B
  const size_t hdr = 2 * wTbytes + 2 * 4608 + 4096 + 4096;  // + zrow page

  // --- pick chunk size Tc (gx packed: 8 B per (m,d)) ---
  int Tc = 64;
  for (int tc = 2048; tc >= 64; tc >>= 1) {
    size_t hBsz  = (size_t)BB * tc * DD * 2;
    size_t xpsz  = (size_t)BB * (tc + KS - 1) * DD * 2;
    size_t uni   = hBsz > xpsz ? hBsz : xpsz;
    size_t need = hdr +
                  (size_t)BB * (tc + KS - 1) * DD * 8 +     // packed gx chunk
                  (size_t)BB * tc * DD * 2 +                // hA
                  uni;                                      // hB / xpadc union
    if (need <= ws_size) { Tc = tc; break; }
  }
  int lgTc = 0; while ((1 << lgTc) < Tc) ++lgTc;
  const int Uc = Tc + KS - 1;
  const int Mc = BB * Tc;
  const int Mg = BB * Uc;

  char* ws = (char*)d_ws;
  unsigned short* wihT = (unsigned short*)ws; ws += wTbytes;
  unsigned short* whhT = (unsigned short*)ws; ws += wTbytes;
  unsigned short* bihB = (unsigned short*)ws; ws += 4608;
  unsigned short* bhhB = (unsigned short*)ws; ws += 4608;
  int* flag            = (int*)ws;            ws += 4096;
  unsigned short* zrow = (unsigned short*)ws; ws += 4096;
  unsigned short* gxc  = (unsigned short*)ws; ws += (size_t)Mg * DD * 8;
  unsigned short* hA   = (unsigned short*)ws; ws += (size_t)Mc * DD * 2;
  unsigned short* hB   = (unsigned short*)ws;       // union with xpadc
  unsigned short* xpadc = hB;

  detect_k<<<1, 64, 0, stream>>>((const uint32_t*)x, flag);
  zero_k<<<8, 256, 0, stream>>>(zrow, 2048);
  transpose_k<<<dim3(ND / 32, DD / 32), dim3(32, 8), 0, stream>>>(w_ih, wihT, DD, ND, flag);
  transpose_k<<<dim3(ND / 32, DD / 32), dim3(32, 8), 0, stream>>>(w_hh, whhT, DD, ND, flag);
  conv_bias<<<(ND + 255) / 256, 256, 0, stream>>>(b_ih, bihB, ND, flag);
  conv_bias<<<(ND + 255) / 256, 256, 0, stream>>>(b_hh, bhhB, ND, flag);

  const int nbmGx = (Mg + 127) / 128;
  const int nbmGru = Mc / 128;

  for (int t0 = 0; t0 < LL; t0 += Tc) {
    // fp32 mode only: materialize padded bf16 x chunk (aliases hB)
    int total8 = Mg * (DD / 8);
    conv_x<<<(total8 + 255) / 256, 256, 0, stream>>>(x, xpadc, Uc, t0, total8, flag);

    // fused: packed gx + GRU step 0 (h0 -> hA)
    gemm_gx<<<nbmGx * NBD, 256, 0, stream>>>(
        (const unsigned short*)x, xpadc, zrow, wihT, bihB, bhhB, gxc, hA,
        Mg, Uc, Tc, t0, flag, nbmGx);

    unsigned short* cur = hA;
    for (int j = 1; j <= 7; ++j) {
      int isFinal = (j == 7);
      void* dst = isFinal ? d_out : (void*)((cur == hA) ? hB : hA);
      int hnBS = isFinal ? LL : Tc;
      int hnOff = isFinal ? t0 : 0;
      gemm_gru_step<<<nbmGru * NBD, 256, 0, stream>>>(
          cur, whhT, bhhB, gxc, Uc, dst, hnBS, hnOff, j, lgTc, flag, isFinal, nbmGru);
      if (!isFinal) cur = (cur == hA) ? hB : hA;
    }
  }
}

// Round 19
// 693.049 us; speedup vs baseline: 1.1843x; 1.0165x over previous
//
#include <hip/hip_runtime.h>
#include <stdint.h>
#include <stddef.h>

using short8 = __attribute__((ext_vector_type(8))) short;
using short4v = __attribute__((ext_vector_type(4))) short;
using f32x4  = __attribute__((ext_vector_type(4))) float;

#define BB 8
#define LL 2048
#define DD 768
#define KS 8
#define ND 2304           // 3*DD
#define NT 12             // DD/64 k-tiles
#define NBD 12            // DD/64 d-blocks

__device__ __forceinline__ float bf2f(unsigned short u) {
  union { uint32_t i; float f; } v; v.i = ((uint32_t)u) << 16; return v.f;
}
__device__ __forceinline__ unsigned short f2bf(float f) {
  union { float f; uint32_t i; } v; v.f = f;
  return (unsigned short)((v.i + 0x7FFFu + ((v.i >> 16) & 1u)) >> 16);
}
__device__ __forceinline__ float sigm(float x) { return 1.0f / (1.0f + __expf(-x)); }
__device__ __forceinline__ float tanh_fast(float x) {
  return 2.0f / (1.0f + __expf(-2.0f * x)) - 1.0f;
}
// global -> LDS DMA, 16B per lane. lds MUST be wave-uniform (HW adds lane*16).
__device__ __forceinline__ void gload_lds16(const void* g, void* lds) {
  __builtin_amdgcn_global_load_lds(
      (const __attribute__((address_space(1))) void*)g,
      (__attribute__((address_space(3))) void*)lds, 16, 0, 0);
}

// group-swizzle: groups of 8 m-blocks x nbn n-blocks; gm fastest within group.
__device__ __forceinline__ void swz_blocks(int bid, int nbm, int nbn,
                                           int* mb, int* nb) {
  int gsz = 8 * nbn;
  int g = bid / gsz;
  int rem = bid - g * gsz;
  int gg = nbm - g * 8; if (gg > 8) gg = 8;
  *nb = rem / gg;
  *mb = g * 8 + (rem - *nb * gg);
}

// ---- zero a small buffer ----------------------------------------------------
__global__ void zero_k(unsigned short* p, int n) {
  int i = blockIdx.x * 256 + threadIdx.x;
  if (i < n) p[i] = 0;
}

// ---- dtype detector: flag=1 if x is bf16 pairs, 0 if fp32 -----------------
__global__ void detect_k(const uint32_t* __restrict__ x, int* __restrict__ flag) {
  int t = threadIdx.x;  // 64 threads
  uint32_t w = x[t * 16];
  int e = (int)((w >> 7) & 0xFF);
  int isbf = (e >= 112 && e <= 136) ? 1 : 0;
  unsigned long long m = __ballot(isbf);
  if (t == 0) *flag = (__popcll(m) >= 32) ? 1 : 0;
}

// ---- transpose [R][C] -> [C][R], dual-dtype in, bf16 out ------------------
__global__ void transpose_k(const void* __restrict__ in,
                            unsigned short* __restrict__ out, int R, int C,
                            const int* __restrict__ flagp) {
  const bool bf = (*flagp != 0);
  __shared__ unsigned short t[32][33];
  int c0 = blockIdx.x * 32, r0 = blockIdx.y * 32;
  int tx = threadIdx.x, ty = threadIdx.y;  // block (32,8)
#pragma unroll
  for (int i = ty; i < 32; i += 8) {
    size_t idx = (size_t)(r0 + i) * C + c0 + tx;
    t[i][tx] = bf ? ((const unsigned short*)in)[idx]
                  : f2bf(((const float*)in)[idx]);
  }
  __syncthreads();
#pragma unroll
  for (int i = ty; i < 32; i += 8)
    out[(size_t)(c0 + i) * R + r0 + tx] = t[tx][i];
}

// ---- bias convert -> bf16 --------------------------------------------------
__global__ void conv_bias(const void* __restrict__ in,
                          unsigned short* __restrict__ out, int n,
                          const int* __restrict__ flagp) {
  const bool bf = (*flagp != 0);
  int i = blockIdx.x * 256 + threadIdx.x;
  if (i >= n) return;
  out[i] = bf ? ((const unsigned short*)in)[i] : f2bf(((const float*)in)[i]);
}

// ---- conv_x (fp32 mode ONLY): build padded bf16 chunk xpadc ---------------
__global__ void conv_x(const void* __restrict__ xv,
                       unsigned short* __restrict__ xpadc,
                       int Uc, int t0, int total8,
                       const int* __restrict__ flagp) {
  if (*flagp != 0) return;  // bf16 mode: gemm_gx reads x directly
  int idx = blockIdx.x * 256 + threadIdx.x;   // one short8 = 8 elems
  if (idx >= total8) return;
  size_t e = (size_t)idx * 8;
  int d = (int)(e % DD);
  size_t ru = e / DD;
  int u = (int)(ru % Uc);
  int b = (int)(ru / Uc);
  int p = t0 + u;
  short8 v = {0, 0, 0, 0, 0, 0, 0, 0};
  if (p >= KS - 1) {
    size_t base = ((size_t)b * LL + (p - (KS - 1))) * DD + d;
    const float* fp = (const float*)xv + base;
    float4 a = *(const float4*)fp, b4 = *(const float4*)(fp + 4);
    v[0] = (short)f2bf(a.x); v[1] = (short)f2bf(a.y);
    v[2] = (short)f2bf(a.z); v[3] = (short)f2bf(a.w);
    v[4] = (short)f2bf(b4.x); v[5] = (short)f2bf(b4.y);
    v[6] = (short)f2bf(b4.z); v[7] = (short)f2bf(b4.w);
  }
  *(short8*)&xpadc[e] = v;
}

// ---- fused gx GEMM + step0: 128m x 64d x 3 gates --------------------------
// Round-16 structure: single LDS buffer, 2 barriers/tile, 3 blocks/CU.
// Writes packed gx [row][d][4]{r,z,n,0} (single 8-B store) and h0 -> hA.
__global__ __launch_bounds__(256, 3) void gemm_gx(
    const unsigned short* __restrict__ xbf, const unsigned short* __restrict__ xpadc,
    const unsigned short* __restrict__ zrow, const unsigned short* __restrict__ WT,
    const unsigned short* __restrict__ bih, const unsigned short* __restrict__ bhh,
    unsigned short* __restrict__ gxp, unsigned short* __restrict__ h0,
    int Mrows, int Uc, int Tcc, int t0, const int* __restrict__ flagp, int nbm) {
  __shared__ __align__(16) unsigned short Al[128 * 64];  // 16 KB
  __shared__ __align__(16) unsigned short Bl[192 * 64];  // 24 KB
  const bool bfm = (*flagp != 0);
  const int tid = threadIdx.x, lane = tid & 63, wv = tid >> 6;
  const int wm = wv >> 1, wd = wv & 1;
  int mb, db; swz_blocks(blockIdx.x, nbm, NBD, &mb, &db);
  const int m0 = mb * 128, d0 = db * 64;
  const int h16 = lane >> 4, l16 = lane & 15;

  const int r0i = tid >> 3;
  const int slotg = (tid & 7) ^ (r0i & 7);
  const unsigned short* asrc[4];
#pragma unroll
  for (int it = 0; it < 4; ++it) {
    int grow = m0 + it * 32 + r0i; if (grow >= Mrows) grow = Mrows - 1;
    if (bfm) {
      int b = grow / Uc, u = grow - b * Uc;
      int p = t0 + u;
      asrc[it] = (p < KS - 1)
          ? (zrow + slotg * 8)
          : (xbf + ((size_t)b * LL + (p - (KS - 1))) * DD + slotg * 8);
    } else {
      asrc[it] = xpadc + (size_t)grow * DD + slotg * 8;
    }
  }
  const unsigned short* bbase = WT + (size_t)(d0 + r0i) * DD + slotg * 8;
  char* aldst = (char*)Al + (wv * 1024);
  char* bldst = (char*)Bl + (wv * 1024);

  f32x4 acc[4][2][3] = {};

  for (int kt = 0; kt < NT; ++kt) {
    const int ko = kt * 64;
#pragma unroll
    for (int it = 0; it < 4; ++it)
      gload_lds16(asrc[it] + ko, aldst + it * 4096);
#pragma unroll
    for (int it = 0; it < 6; ++it) {
      const size_t boff = (size_t)(it >> 1) * (DD * DD) + (size_t)(it & 1) * (32 * DD);
      gload_lds16(bbase + boff + ko, bldst + it * 4096);
    }
    __syncthreads();
#pragma unroll
    for (int s = 0; s < 2; ++s) {
      short8 af[4];
#pragma unroll
      for (int i = 0; i < 4; ++i) {
        int row = wm * 64 + i * 16 + l16;
        af[i] = *(const short8*)&Al[row * 64 + (((s * 4 + h16) ^ (row & 7)) * 8)];
      }
      short8 bfr[2][3];
#pragma unroll
      for (int jd = 0; jd < 2; ++jd)
#pragma unroll
        for (int g = 0; g < 3; ++g) {
          int row = g * 64 + wd * 32 + jd * 16 + l16;
          bfr[jd][g] = *(const short8*)&Bl[row * 64 + (((s * 4 + h16) ^ (row & 7)) * 8)];
        }
#pragma unroll
      for (int i = 0; i < 4; ++i)
#pragma unroll
        for (int jd = 0; jd < 2; ++jd)
#pragma unroll
          for (int g = 0; g < 3; ++g)
            acc[i][jd][g] = __builtin_amdgcn_mfma_f32_16x16x32_bf16(af[i], bfr[jd][g], acc[i][jd][g], 0, 0, 0);
    }
    if (kt + 1 < NT) __syncthreads();
  }

  const int b0 = m0 / Uc;
  const int u00 = m0 - b0 * Uc;
#pragma unroll
  for (int jd = 0; jd < 2; ++jd) {
    int d = d0 + wd * 32 + jd * 16 + l16;
    float bir = bf2f(bih[d]), biz = bf2f(bih[DD + d]), bin_ = bf2f(bih[2 * DD + d]);
    float bhr = bf2f(bhh[d]), bhz = bf2f(bhh[DD + d]), bhn = bf2f(bhh[2 * DD + d]);
#pragma unroll
    for (int i = 0; i < 4; ++i) {
      int mbase = m0 + wm * 64 + i * 16 + 4 * h16;
#pragma unroll
      for (int r2 = 0; r2 < 4; ++r2) {
        int m = mbase + r2;
        if (m >= Mrows) continue;
        float gr = acc[i][jd][0][r2] + bir;
        float gz = acc[i][jd][1][r2] + biz;
        float gn = acc[i][jd][2][r2] + bin_;
        short4v pk;
        pk[0] = (short)f2bf(gr); pk[1] = (short)f2bf(gz);
        pk[2] = (short)f2bf(gn); pk[3] = 0;
        *(short4v*)(gxp + (size_t)m * (DD * 4) + d * 4) = pk;
        int uu = u00 + (m - m0);
        int b = b0;
        if (uu >= Uc) { b += 1; uu -= Uc; }
        if (uu < Tcc) {
          float r = sigm(gr + bhr);
          float z = sigm(gz + bhz);
          float n = tanh_fast(gn + r * bhn);
          h0[((size_t)b * Tcc + uu) * DD + d] = f2bf((1.0f - z) * n);
        }
      }
    }
  }
}

// ---- fused GEMM + GRU step j (j=1..7): round-16 structure verbatim --------
__global__ __launch_bounds__(256, 3) void gemm_gru_step(
    const unsigned short* __restrict__ Hc, const unsigned short* __restrict__ WT,
    const unsigned short* __restrict__ bhh, const unsigned short* __restrict__ gxp,
    int Uc, void* __restrict__ Hn, int hnBS, int hnOff, int j, int lgTc,
    const int* __restrict__ flagp, int isFinal, int nbm) {
  __shared__ __align__(16) unsigned short Al[128 * 64];  // 16 KB
  __shared__ __align__(16) unsigned short Bl[192 * 64];  // 24 KB
  const bool bfm = (*flagp != 0);
  const int tid = threadIdx.x, lane = tid & 63, wv = tid >> 6;
  const int wm = wv >> 1, wd = wv & 1;
  int mb, db; swz_blocks(blockIdx.x, nbm, NBD, &mb, &db);
  const int m0 = mb * 128, d0 = db * 64;
  const int h16 = lane >> 4, l16 = lane & 15;
  const int tmask = (1 << lgTc) - 1;

  const int r0i = tid >> 3;
  const int slotg = (tid & 7) ^ (r0i & 7);
  const unsigned short* abase = Hc + (size_t)(m0 + r0i) * DD + slotg * 8;
  const unsigned short* bbase = WT + (size_t)(d0 + r0i) * DD + slotg * 8;
  char* aldst = (char*)Al + (wv * 1024);
  char* bldst = (char*)Bl + (wv * 1024);

  f32x4 acc[4][2][3] = {};

  for (int kt = 0; kt < NT; ++kt) {
    const int ko = kt * 64;
#pragma unroll
    for (int it = 0; it < 4; ++it)
      gload_lds16(abase + (size_t)it * (32 * DD) + ko, aldst + it * 4096);
#pragma unroll
    for (int it = 0; it < 6; ++it) {
      const size_t boff = (size_t)(it >> 1) * (DD * DD) + (size_t)(it & 1) * (32 * DD);
      gload_lds16(bbase + boff + ko, bldst + it * 4096);
    }
    __syncthreads();
#pragma unroll
    for (int s = 0; s < 2; ++s) {
      short8 af[4];
#pragma unroll
      for (int i = 0; i < 4; ++i) {
        int row = wm * 64 + i * 16 + l16;
        af[i] = *(const short8*)&Al[row * 64 + (((s * 4 + h16) ^ (row & 7)) * 8)];
      }
      short8 bfr[2][3];
#pragma unroll
      for (int jd = 0; jd < 2; ++jd)
#pragma unroll
        for (int g = 0; g < 3; ++g) {
          int row = g * 64 + wd * 32 + jd * 16 + l16;
          bfr[jd][g] = *(const short8*)&Bl[row * 64 + (((s * 4 + h16) ^ (row & 7)) * 8)];
        }
#pragma unroll
      for (int i = 0; i < 4; ++i)
#pragma unroll
        for (int jd = 0; jd < 2; ++jd)
#pragma unroll
          for (int g = 0; g < 3; ++g)
            acc[i][jd][g] = __builtin_amdgcn_mfma_f32_16x16x32_bf16(af[i], bfr[jd][g], acc[i][jd][g], 0, 0, 0);
    }
    if (kt + 1 < NT) __syncthreads();
  }

#pragma unroll
  for (int jd = 0; jd < 2; ++jd) {
    int d = d0 + wd * 32 + jd * 16 + l16;
    float br = bf2f(bhh[d]), bz = bf2f(bhh[DD + d]), bn = bf2f(bhh[2 * DD + d]);
#pragma unroll
    for (int i = 0; i < 4; ++i) {
      int mbase = m0 + wm * 64 + i * 16 + 4 * h16;
#pragma unroll
      for (int r2 = 0; r2 < 4; ++r2) {
        int m = mbase + r2;
        int b = m >> lgTc, t = m & tmask;
        size_t gxrow = (size_t)b * Uc + t + j;
        short4v pk = *(const short4v*)(gxp + gxrow * (DD * 4) + d * 4);
        float xr = bf2f((unsigned short)pk[0]);
        float xz = bf2f((unsigned short)pk[1]);
        float xn = bf2f((unsigned short)pk[2]);
        float gr = acc[i][jd][0][r2] + br;
        float gz = acc[i][jd][1][r2] + bz;
        float gn = acc[i][jd][2][r2] + bn;
        float rr = sigm(xr + gr);
        float zz = sigm(xz + gz);
        float nn = tanh_fast(xn + rr * gn);
        float ho = bf2f(Hc[(size_t)m * DD + d]);
        float val = (1.0f - zz) * nn + zz * ho;
        size_t hnrow = (size_t)b * hnBS + hnOff + t;
        if (isFinal && !bfm) ((float*)Hn)[hnrow * DD + d] = val;
        else ((unsigned short*)Hn)[hnrow * DD + d] = f2bf(val);
      }
    }
  }
}

extern "C" void kernel_launch(void* const* d_in, const int* in_sizes, int n_in,
                              void* d_out, int out_size, void* d_ws, size_t ws_size,
                              hipStream_t stream) {
  const void* x    = d_in[0];
  const void* w_ih = d_in[1];
  const void* w_hh = d_in[2];
  const void* b_ih = d_in[3];
  const void* b_hh = d_in[4];

  const size_t wTbytes = (size_t)ND * DD * 2;  // 3,538,944 B
  const size_t hdr = 2 * wTbytes + 2 * 4608 + 4096 + 4096;  // + zrow page

  // --- pick chunk size Tc (gx packed: 8 B per (m,d)) ---
  int Tc = 64;
  for (int tc = 2048; tc >= 64; tc >>= 1) {
    size_t hBsz  = (size_t)BB * tc * DD * 2;
    size_t xpsz  = (size_t)BB * (tc + KS - 1) * DD * 2;
    size_t uni   = hBsz > xpsz ? hBsz : xpsz;
    size_t need = hdr +
                  (size_t)BB * (tc + KS - 1) * DD * 8 +     // packed gx chunk
                  (size_t)BB * tc * DD * 2 +                // hA
                  uni;                                      // hB / xpadc union
    if (need <= ws_size) { Tc = tc; break; }
  }
  int lgTc = 0; while ((1 << lgTc) < Tc) ++lgTc;
  const int Uc = Tc + KS - 1;
  const int Mc = BB * Tc;
  const int Mg = BB * Uc;

  char* ws = (char*)d_ws;
  unsigned short* wihT = (unsigned short*)ws; ws += wTbytes;
  unsigned short* whhT = (unsigned short*)ws; ws += wTbytes;
  unsigned short* bihB = (unsigned short*)ws; ws += 4608;
  unsigned short* bhhB = (unsigned short*)ws; ws += 4608;
  int* flag            = (int*)ws;            ws += 4096;
  unsigned short* zrow = (unsigned short*)ws; ws += 4096;
  unsigned short* gxc  = (unsigned short*)ws; ws += (size_t)Mg * DD * 8;
  unsigned short* hA   = (unsigned short*)ws; ws += (size_t)Mc * DD * 2;
  unsigned short* hB   = (unsigned short*)ws;       // union with xpadc
  unsigned short* xpadc = hB;

  detect_k<<<1, 64, 0, stream>>>((const uint32_t*)x, flag);
  zero_k<<<8, 256, 0, stream>>>(zrow, 2048);
  transpose_k<<<dim3(ND / 32, DD / 32), dim3(32, 8), 0, stream>>>(w_ih, wihT, DD, ND, flag);
  transpose_k<<<dim3(ND / 32, DD / 32), dim3(32, 8), 0, stream>>>(w_hh, whhT, DD, ND, flag);
  conv_bias<<<(ND + 255) / 256, 256, 0, stream>>>(b_ih, bihB, ND, flag);
  conv_bias<<<(ND + 255) / 256, 256, 0, stream>>>(b_hh, bhhB, ND, flag);

  const int nbmGx = (Mg + 127) / 128;
  const int nbmGru = Mc / 128;

  for (int t0 = 0; t0 < LL; t0 += Tc) {
    // fp32 mode only: materialize padded bf16 x chunk (aliases hB)
    int total8 = Mg * (DD / 8);
    conv_x<<<(total8 + 255) / 256, 256, 0, stream>>>(x, xpadc, Uc, t0, total8, flag);

    // fused: packed gx + GRU step 0 (h0 -> hA)
    gemm_gx<<<nbmGx * NBD, 256, 0, stream>>>(
        (const unsigned short*)x, xpadc, zrow, wihT, bihB, bhhB, gxc, hA,
        Mg, Uc, Tc, t0, flag, nbmGx);

    unsigned short* cur = hA;
    for (int j = 1; j <= 7; ++j) {
      int isFinal = (j == 7);
      void* dst = isFinal ? d_out : (void*)((cur == hA) ? hB : hA);
      int hnBS = isFinal ? LL : Tc;
      int hnOff = isFinal ? t0 : 0;
      gemm_gru_step<<<nbmGru * NBD, 256, 0, stream>>>(
          cur, whhT, bhhB, gxc, Uc, dst, hnBS, hnOff, j, lgTc, flag, isFinal, nbmGru);
      if (!isFinal) cur = (cur == hA) ? hB : hA;
    }
  }
}